// Round 1
// baseline (354.292 us; speedup 1.0000x reference)
//
#include <hip/hip_runtime.h>

// WarpLayer: bilinear backward warp.
// image [B,H,W,C] f32, flow [B,H,W,2] f32 -> out [B,H,W,C] f32
// q = grid - flow; y0 = clip(floor(qy),0,H-2); alpha = clip(q - floor_clipped, 0, 1)
// out = lerp over 4 corners.
//
// Layout: C=32 innermost => per corner-row (tl|tr) is 256 contiguous bytes
// (x1 == x0+1 always). 4 threads per pixel, each owning 8 channels
// (2 float4 per corner), so a 64-lane wave covers 16 pixels with coalesced
// loads. Output stores are nontemporal (never re-read) to keep L2 for the
// image gather's y/x-overlap reuse. All index math in 32-bit (max idx 12.6M).

typedef float f4 __attribute__((ext_vector_type(4)));

#define WB 8
#define WH 384
#define WW 512
#define WC 32

__global__ __launch_bounds__(256) void warp_kernel(
    const float* __restrict__ image,
    const float* __restrict__ flow,
    float* __restrict__ out)
{
    const int tid = blockIdx.x * 256 + threadIdx.x;
    const int cg  = (tid & 3) * 2;  // float4-group index within pixel: {0,2,4,6}
    const int pix = tid >> 2;       // linear pixel index b*H*W + h*W + w

    const int w  = pix & (WW - 1);  // W = 512 = 2^9
    const int bh = pix >> 9;
    const int h  = bh % WH;
    const int b  = bh / WH;

    // flow[..,0] = dy, flow[..,1] = dx ; q = grid - flow
    const float2 f = ((const float2*)flow)[pix];
    const float qy = (float)h - f.x;
    const float qx = (float)w - f.y;

    const float fly = fminf(fmaxf(floorf(qy), 0.0f), (float)(WH - 2));
    const float flx = fminf(fmaxf(floorf(qx), 0.0f), (float)(WW - 2));
    const int y0 = (int)fly;
    const int x0 = (int)flx;
    const float ay = fminf(fmaxf(qy - fly, 0.0f), 1.0f);
    const float ax = fminf(fmaxf(qx - flx, 0.0f), 1.0f);

    // float4-unit indices: pixel p has 8 float4 groups; this thread owns cg, cg+1
    const f4* __restrict__ img4 = (const f4*)image;
    const int base  = ((b * WH + y0) * WW + x0) * 8 + cg; // max ~12.58M, fits i32
    const int baseb = base + WW * 8;                      // y0+1 row

    // top row: tl and tr (x0, x0+1) — adjacent 128B blocks
    const f4 tl0 = img4[base];
    const f4 tl1 = img4[base + 1];
    const f4 tr0 = img4[base + 8];
    const f4 tr1 = img4[base + 9];
    // bottom row
    const f4 bl0 = img4[baseb];
    const f4 bl1 = img4[baseb + 1];
    const f4 br0 = img4[baseb + 8];
    const f4 br1 = img4[baseb + 9];

    const f4 top0 = tl0 + ax * (tr0 - tl0);
    const f4 bot0 = bl0 + ax * (br0 - bl0);
    const f4 top1 = tl1 + ax * (tr1 - tl1);
    const f4 bot1 = bl1 + ax * (br1 - bl1);
    const f4 r0 = top0 + ay * (bot0 - top0);
    const f4 r1 = top1 + ay * (bot1 - top1);

    f4* out4 = (f4*)out;
    const int obase = pix * 8 + cg;
    __builtin_nontemporal_store(r0, out4 + obase);
    __builtin_nontemporal_store(r1, out4 + obase + 1);
}

extern "C" void kernel_launch(void* const* d_in, const int* in_sizes, int n_in,
                              void* d_out, int out_size, void* d_ws, size_t ws_size,
                              hipStream_t stream)
{
    const float* image = (const float*)d_in[0];
    const float* flow  = (const float*)d_in[1];
    float* out = (float*)d_out;

    const int nthreads = WB * WH * WW * (WC / 8); // 6,291,456 (4 threads/pixel)
    const int block = 256;
    const int grid = nthreads / block;            // 24,576 exactly, no tail
    warp_kernel<<<grid, block, 0, stream>>>(image, flow, out);
}

// Round 2
// 344.727 us; speedup vs baseline: 1.0277x; 1.0277x over previous
//
#include <hip/hip_runtime.h>

// WarpLayer: bilinear backward warp.
// image [B,H,W,C] f32, flow [B,H,W,2] f32 -> out [B,H,W,C] f32
// q = grid - flow; y0 = clip(floor(qy),0,H-2); alpha = clip(q - floor_clipped, 0, 1)
// out = lerp over 4 corners.
//
// Layout: C=32 innermost => each corner pixel = 128 contiguous bytes.
// 8 threads per pixel (one float4 channel-group each): a 64-lane wave covers
// 8 pixels; each gather instruction reads 8 scattered-but-internally-
// contiguous 128B segments. 32-bit index math throughout.
//
// XCD swizzle: flow ~ N(0,1) so the gather is near-identity (±few px jitter)
// with strong row reuse. Default round-robin block->XCD dispatch pulls every
// image row into all 8 per-XCD L2s (~8x duplicated L3 traffic). Swizzling so
// each XCD owns a contiguous 1/8 pixel slab (= exactly one batch image)
// confines each XCD's gather window (~5 rows ~ 320 KB) to its own L2.
//
// NT stores: output is never re-read; keep L2 for the gather's reuse window.

typedef float f4 __attribute__((ext_vector_type(4)));

#define WB 8
#define WH 384
#define WW 512
#define WC 32
#define NBLK (WB * WH * WW * (WC / 4) / 256)  // 49,152 blocks
#define BPX  (NBLK / 8)                        // 6,144 blocks per XCD slab

__global__ __launch_bounds__(256) void warp_kernel(
    const float* __restrict__ image,
    const float* __restrict__ flow,
    float* __restrict__ out)
{
    // Bijective XCD swizzle: XCD k (= bid % 8 under round-robin dispatch)
    // processes contiguous block slab [k*BPX, (k+1)*BPX).
    const int bsw = (blockIdx.x & 7) * BPX + (blockIdx.x >> 3);
    const int tid = bsw * 256 + threadIdx.x;
    const int cg  = tid & 7;   // float4 channel-group within the pixel
    const int pix = tid >> 3;  // linear pixel index b*H*W + h*W + w

    const int w  = pix & (WW - 1);  // W = 512 = 2^9
    const int bh = pix >> 9;
    const int h  = bh % WH;
    const int b  = bh / WH;

    // flow[..,0] = dy, flow[..,1] = dx ; q = grid - flow
    const float2 f = ((const float2*)flow)[pix];
    const float qy = (float)h - f.x;
    const float qx = (float)w - f.y;

    const float fly = fminf(fmaxf(floorf(qy), 0.0f), (float)(WH - 2));
    const float flx = fminf(fmaxf(floorf(qx), 0.0f), (float)(WW - 2));
    const int y0 = (int)fly;
    const int x0 = (int)flx;
    const float ay = fminf(fmaxf(qy - fly, 0.0f), 1.0f);
    const float ax = fminf(fmaxf(qx - flx, 0.0f), 1.0f);

    // float4-unit indices: pixel p has 8 float4 groups
    const f4* __restrict__ img4 = (const f4*)image;
    const int base = ((b * WH + y0) * WW + x0) * 8 + cg; // max ~12.58M, fits i32
    const f4 tl = img4[base];
    const f4 tr = img4[base + 8];            // x0+1
    const f4 bl = img4[base + WW * 8];       // y0+1
    const f4 br = img4[base + WW * 8 + 8];

    const f4 top = tl + ax * (tr - tl);
    const f4 bot = bl + ax * (br - bl);
    const f4 r   = top + ay * (bot - top);

    __builtin_nontemporal_store(r, (f4*)out + pix * 8 + cg);
}

extern "C" void kernel_launch(void* const* d_in, const int* in_sizes, int n_in,
                              void* d_out, int out_size, void* d_ws, size_t ws_size,
                              hipStream_t stream)
{
    const float* image = (const float*)d_in[0];
    const float* flow  = (const float*)d_in[1];
    float* out = (float*)d_out;

    warp_kernel<<<NBLK, 256, 0, stream>>>(image, flow, out);
}